// Round 8
// baseline (19126.387 us; speedup 1.0000x reference)
//
#include <hip/hip_runtime.h>
#include <hip/hip_bf16.h>

// ---------------- types ----------------
typedef _Float16 half2_t __attribute__((ext_vector_type(2)));
typedef _Float16 half8_t __attribute__((ext_vector_type(8)));
typedef float float4_t __attribute__((ext_vector_type(4)));

#define SEQ   8192
#define ISZ   512
#define HID   2048
#define G4H   8192   // 4*HID
#define NB    256    // persistent blocks (== CU count)

#if __has_builtin(__builtin_amdgcn_fdot2)
#define DOT2(a, b, c) __builtin_amdgcn_fdot2((a), (b), (c), false)
#else
static __device__ __forceinline__ float DOT2(half2_t a, half2_t b, float c) {
    return c + (float)a.x * (float)b.x + (float)a.y * (float)b.y;
}
#endif

#if __has_builtin(__builtin_amdgcn_rcpf)
#define RCP(x) __builtin_amdgcn_rcpf(x)
#else
#define RCP(x) (1.0f / (x))
#endif

// relaxed agent-scope (sc1, device-coherent) accesses — no fences, no RMW
static __device__ __forceinline__ unsigned long long ld_u64(const void* p) {
    return __hip_atomic_load((const unsigned long long*)p, __ATOMIC_RELAXED,
                             __HIP_MEMORY_SCOPE_AGENT);
}
static __device__ __forceinline__ void st_u64(void* p, unsigned long long v) {
    __hip_atomic_store((unsigned long long*)p, v, __ATOMIC_RELAXED,
                       __HIP_MEMORY_SCOPE_AGENT);
}

// DPP butterfly add: x + perm(x).
template <int CTRL>
static __device__ __forceinline__ float dpp_add(float x) {
    int v = __builtin_amdgcn_update_dpp(0, __builtin_bit_cast(int, x), CTRL, 0xF,
                                        0xF, true);
    return x + __builtin_bit_cast(float, v);
}
#define DPP_XOR1  0xB1   // quad_perm [1,0,3,2]
#define DPP_XOR2  0x4E   // quad_perm [2,3,0,1]
#define DPP_XOR4  0x141  // row_half_mirror
#define DPP_XOR8  0x128  // row_ror:8 (exact lane s <-> s+8 within row16)

// ---------------- f32 -> f16 convert ----------------
__global__ __launch_bounds__(256) void cvt_f32_f16(const float* __restrict__ in,
                                                   _Float16* __restrict__ out, int n) {
    int i = (blockIdx.x * 256 + threadIdx.x) * 4;
    if (i < n) {
        float4 v = *(const float4*)(in + i);
        out[i + 0] = (_Float16)v.x;
        out[i + 1] = (_Float16)v.y;
        out[i + 2] = (_Float16)v.z;
        out[i + 3] = (_Float16)v.w;
    }
}

// ---------------- init words (zero => {h=0, tag=0} == "h_0 valid") ----------------
// words region: [2][1024] logical words, each in its OWN 64-B line => 128 KB.
__global__ __launch_bounds__(256) void init_state(unsigned long long* __restrict__ words) {
    int i = blockIdx.x * 256 + threadIdx.x;
    if (i < 16384) words[i] = 0ull;
}

// ---------------- x_proj GEMM: C = A @ B^T, epilogue scattered into xp2 ----------
// xp2 layout: xp2[t][b*32 + g*8 + r] where r = gate*2 + (elem&1), g = (elem>>1)&3,
// b = elem>>3. One 64-B line per block-step.
__global__ __launch_bounds__(256) void gemm_xproj(const _Float16* __restrict__ A,  // [SEQ][ISZ]
                                                  const _Float16* __restrict__ B,  // [G4H][ISZ]
                                                  _Float16* __restrict__ C) {      // [SEQ][G4H] permuted
    __shared__ _Float16 As[128 * 40];
    __shared__ _Float16 Bs[128 * 40];
    const int tid = threadIdx.x;
    const int bm = blockIdx.y, bn = blockIdx.x;
    const int wave = tid >> 6, lane = tid & 63;
    const int wr = wave >> 1, wc = wave & 1;
    const int l15 = lane & 15, lq = lane >> 4;

    float4_t acc[4][4];
#pragma unroll
    for (int im = 0; im < 4; im++)
#pragma unroll
        for (int in = 0; in < 4; in++)
#pragma unroll
            for (int r = 0; r < 4; r++) acc[im][in][r] = 0.f;

    for (int kt = 0; kt < ISZ; kt += 32) {
        __syncthreads();
#pragma unroll
        for (int ld = 0; ld < 2; ld++) {
            int c = tid + ld * 256;
            int r = c >> 2, ko = (c & 3) * 8;
            uint4 av = *(const uint4*)(A + (size_t)(bm * 128 + r) * ISZ + kt + ko);
            *(uint4*)(As + r * 40 + ko) = av;
            uint4 bv = *(const uint4*)(B + (size_t)(bn * 128 + r) * ISZ + kt + ko);
            *(uint4*)(Bs + r * 40 + ko) = bv;
        }
        __syncthreads();
        half8_t af[4], bf[4];
#pragma unroll
        for (int im = 0; im < 4; im++)
            af[im] = *(half8_t*)(As + (wr * 64 + im * 16 + l15) * 40 + lq * 8);
#pragma unroll
        for (int in = 0; in < 4; in++)
            bf[in] = *(half8_t*)(Bs + (wc * 64 + in * 16 + l15) * 40 + lq * 8);
#pragma unroll
        for (int im = 0; im < 4; im++)
#pragma unroll
            for (int in = 0; in < 4; in++)
                acc[im][in] = __builtin_amdgcn_mfma_f32_16x16x32_f16(af[im], bf[in], acc[im][in], 0, 0, 0);
    }
#pragma unroll
    for (int im = 0; im < 4; im++) {
        int mg = bm * 128 + wr * 64 + im * 16 + lq * 4;
#pragma unroll
        for (int in = 0; in < 4; in++) {
            int ng = bn * 128 + wc * 64 + in * 16 + l15;
            int gate = ng >> 11;
            int e = ng & 2047;
            int col2 = (e >> 3) * 32 + ((e >> 1) & 3) * 8 + gate * 2 + (e & 1);
#pragma unroll
            for (int r = 0; r < 4; r++)
                C[(size_t)(mg + r) * G4H + col2] = (_Float16)acc[im][in][r];
        }
    }
}

// ---------------- persistent LSTM recurrence ----------------
// Block b owns h[8b..8b+8). Wave g owns all 4 gates of elements {2g, 2g+1};
// each wave publishes one self-validating word {tag32 | h_e1 | h_e0}.
// NEW (R8): word id s = b*4+g lives at u64-index s*8 — its OWN 64-B line.
// Per poll round each line now sees 256 requests (1/consumer block), not 1024.
// Poll rotation: wave g lane j polls block 64g+((j+b)&63)'s 4 words (4 lines).
__global__ __launch_bounds__(256, 1) void lstm_persist(
    const float* __restrict__ Whh,   // [G4H][HID] f32
    const float* __restrict__ b_ih, const float* __restrict__ b_hh,
    const _Float16* __restrict__ xp, // [SEQ][G4H] f16, permuted layout
    const float* __restrict__ fcw, const float* __restrict__ fcb,
    unsigned long long* __restrict__ words,  // [2][1024] words @64-B stride
    float* __restrict__ out) {
    const int b = blockIdx.x, tid = threadIdx.x;
    const int g = tid >> 6, lane = tid & 63;
    const int pblk = (g << 6) | ((lane + b) & 63);  // block this lane polls/stages

    __shared__ unsigned h_lds32[2][1280];  // parity x (64 units x 20 dwords)

    // --- prologue: weight slice into registers (f32 -> f16) ---
    half2_t w[8][16];
#pragma unroll
    for (int r = 0; r < 8; r++) {
        const float* wp =
            Whh + (size_t)((r >> 1) * HID + b * 8 + 2 * g + (r & 1)) * HID + lane * 32;
#pragma unroll
        for (int i = 0; i < 16; i++) {
            float2 f = *(const float2*)(wp + i * 2);
            half2_t h2;
            h2.x = (_Float16)f.x;
            h2.y = (_Float16)f.y;
            w[r][i] = h2;
        }
    }
    float bias_r = 0.f;
    if (lane < 8) {
        int row = ((lane >> 1) & 3) * HID + b * 8 + 2 * g + (lane & 1);
        bias_r = b_ih[row] + b_hh[row];
    }
    float c_reg = 0.f;  // cell state of elem 2g+(lane&1)

    const int s_dw = (pblk >> 2) * 20 + (pblk & 3) * 4;  // LDS stage dst (dwords)
    const int xpbase = b * 32 + g * 8;                   // + lane (lanes 0..7)
    const int pw = pblk * 32;                            // u64-index of pblk's word 0

    for (int t = 0; t < SEQ; ++t) {
        const unsigned ut = (unsigned)t;
        const int par = t & 1;
        const unsigned long long* wbase = words + (size_t)par * 8192;

        // x_proj prefetch: one 64-B line per block-step (permuted layout)
        float xpv = 0.f;
        if (lane < 8) xpv = (float)xp[(size_t)t * G4H + xpbase + lane];

        // poll own block's 4 self-validating words (4 separate 64-B lines)
        unsigned long long v0, v1, v2, v3;
        for (;;) {
            v0 = ld_u64(wbase + pw + 0);
            v1 = ld_u64(wbase + pw + 8);
            v2 = ld_u64(wbase + pw + 16);
            v3 = ld_u64(wbase + pw + 24);
            bool ok = ((unsigned)(v0 >> 32) >= ut) && ((unsigned)(v1 >> 32) >= ut) &&
                      ((unsigned)(v2 >> 32) >= ut) && ((unsigned)(v3 >> 32) >= ut);
            if (__all(ok)) break;
            __builtin_amdgcn_s_sleep(1);
        }

        // stage 8 halves of block pblk into parity LDS buffer (one b128)
        *(uint4*)&h_lds32[par][s_dw] =
            make_uint4((unsigned)v0, (unsigned)v1, (unsigned)v2, (unsigned)v3);
        __syncthreads();  // the ONLY barrier: h_t fully staged

        // read slice [lane*32, lane*32+32) as 4 x b128
        union {
            uint4 q[4];
            half2_t h2[16];
        } hu;
        const uint4* hp4 = (const uint4*)((const char*)&h_lds32[par][0] + 80 * lane);
#pragma unroll
        for (int i = 0; i < 4; i++) hu.q[i] = hp4[i];

        // matvec: 8 rows x 32 cols per lane
        float acc[8];
#pragma unroll
        for (int r = 0; r < 8; r++) {
            float a = 0.f;
#pragma unroll
            for (int i = 0; i < 16; i++) a = DOT2(w[r][i], hu.h2[i], a);
            acc[r] = a;
        }
        // reduce: DPP xor1/2/4, select, DPP xor8, shfl 16/32
#pragma unroll
        for (int r = 0; r < 8; r++) {
            acc[r] = dpp_add<DPP_XOR1>(acc[r]);
            acc[r] = dpp_add<DPP_XOR2>(acc[r]);
            acc[r] = dpp_add<DPP_XOR4>(acc[r]);
        }
        float u;
        {
            int s = lane & 7;
            float u01 = (s & 1) ? acc[1] : acc[0];
            float u23 = (s & 1) ? acc[3] : acc[2];
            float u45 = (s & 1) ? acc[5] : acc[4];
            float u67 = (s & 1) ? acc[7] : acc[6];
            float ua = (s & 2) ? u23 : u01;
            float ub = (s & 2) ? u67 : u45;
            u = (s & 4) ? ub : ua;
        }
        u = dpp_add<DPP_XOR8>(u);
        u += __shfl_xor(u, 16, 64);
        u += __shfl_xor(u, 32, 64);
        u += bias_r + xpv;  // valid in lanes 0..7 (sources of the gate shfls)

        // gates: rows [i_e0,i_e1,f_e0,f_e1,g_e0,g_e1,o_e0,o_e1] in lanes 0..7
        {
            int base = lane & 1;
            float gi = __shfl(u, base + 0, 64);
            float gf = __shfl(u, base + 2, 64);
            float gg = __shfl(u, base + 4, 64);
            float go = __shfl(u, base + 6, 64);
            float si = RCP(1.f + __expf(-gi));
            float sf = RCP(1.f + __expf(-gf));
            float so = RCP(1.f + __expf(-go));
            float tg = 1.f - 2.f * RCP(1.f + __expf(2.f * gg));
            c_reg = sf * c_reg + si * tg;
            float tc = 1.f - 2.f * RCP(1.f + __expf(2.f * c_reg));
            float h = so * tc;
            _Float16 hf = (_Float16)h;
            unsigned pk = *(unsigned short*)&hf;
            unsigned pk1 = __shfl(pk, 1, 64);
            if (lane == 0) {
                unsigned lo = pk | (pk1 << 16);
                unsigned long long wword =
                    (unsigned long long)lo | ((unsigned long long)(ut + 1) << 32);
                st_u64(words + (size_t)((t + 1) & 1) * 8192 + (b * 4 + g) * 8, wword);
            }
        }
        // parity-double-buffered LDS + B1 ordering make cross-step reuse race-free
    }

    // --- final fc on h_SEQ (parity 0) by block 0 ---
    if (b == 0) {
        const int par = SEQ & 1;
        const unsigned long long* wbase = words + (size_t)par * 8192;
        unsigned long long v0, v1, v2, v3;
        for (;;) {
            v0 = ld_u64(wbase + pw + 0);
            v1 = ld_u64(wbase + pw + 8);
            v2 = ld_u64(wbase + pw + 16);
            v3 = ld_u64(wbase + pw + 24);
            bool ok = ((unsigned)(v0 >> 32) >= (unsigned)SEQ) &&
                      ((unsigned)(v1 >> 32) >= (unsigned)SEQ) &&
                      ((unsigned)(v2 >> 32) >= (unsigned)SEQ) &&
                      ((unsigned)(v3 >> 32) >= (unsigned)SEQ);
            if (__all(ok)) break;
            __builtin_amdgcn_s_sleep(1);
        }
        *(uint4*)&h_lds32[par][s_dw] =
            make_uint4((unsigned)v0, (unsigned)v1, (unsigned)v2, (unsigned)v3);
        __syncthreads();
        if (g == 0) {
            union {
                uint4 q[4];
                half2_t h2[16];
            } hu;
            const uint4* hp4 = (const uint4*)((const char*)&h_lds32[par][0] + 80 * lane);
#pragma unroll
            for (int i = 0; i < 4; i++) hu.q[i] = hp4[i];
            float s = 0.f;
            const float* fw = fcw + lane * 32;
#pragma unroll
            for (int i = 0; i < 16; i++)
                s += (float)hu.h2[i].x * fw[2 * i] + (float)hu.h2[i].y * fw[2 * i + 1];
#pragma unroll
            for (int off = 1; off < 64; off <<= 1) s += __shfl_xor(s, off, 64);
            if (lane == 0) out[0] = s + fcb[0];
        }
    }
}

// ---------------- launch ----------------
extern "C" void kernel_launch(void* const* d_in, const int* in_sizes, int n_in,
                              void* d_out, int out_size, void* d_ws, size_t ws_size,
                              hipStream_t stream) {
    const float* input = (const float*)d_in[0];  // [SEQ][ISZ]
    const float* W_ih = (const float*)d_in[1];   // [G4H][ISZ]
    const float* W_hh = (const float*)d_in[2];   // [G4H][HID]
    const float* b_ih = (const float*)d_in[3];
    const float* b_hh = (const float*)d_in[4];
    const float* fc_w = (const float*)d_in[5];
    const float* fc_b = (const float*)d_in[6];
    float* out = (float*)d_out;

    char* ws = (char*)d_ws;
    _Float16* xp16 = (_Float16*)ws;               // 134,217,728 B
    _Float16* A16 = (_Float16*)(ws + 134217728);  // 8 MB (dead after gemm)
    _Float16* B16 = (_Float16*)(ws + 142606336);  // 8 MB (dead after gemm)
    // words overlay the dead A16 region (init_state runs AFTER gemm): 128 KB
    unsigned long long* words = (unsigned long long*)(ws + 134217728);

    cvt_f32_f16<<<(SEQ * ISZ) / 1024, 256, 0, stream>>>(input, A16, SEQ * ISZ);
    cvt_f32_f16<<<(G4H * ISZ) / 1024, 256, 0, stream>>>(W_ih, B16, G4H * ISZ);

    dim3 gg(G4H / 128, SEQ / 128);
    gemm_xproj<<<gg, 256, 0, stream>>>(A16, B16, xp16);

    init_state<<<64, 256, 0, stream>>>(words);  // after gemm: A16 region is dead

    lstm_persist<<<NB, 256, 0, stream>>>(W_hh, b_ih, b_hh, xp16, fc_w, fc_b,
                                         words, out);
}

// Round 9
// 15959.250 us; speedup vs baseline: 1.1985x; 1.1985x over previous
//
#include <hip/hip_runtime.h>
#include <hip/hip_bf16.h>

// ---------------- types ----------------
typedef _Float16 half2_t __attribute__((ext_vector_type(2)));
typedef _Float16 half8_t __attribute__((ext_vector_type(8)));
typedef float float4_t __attribute__((ext_vector_type(4)));

#define SEQ   8192
#define ISZ   512
#define HID   2048
#define G4H   8192   // 4*HID
#define NB    256    // persistent blocks (== CU count)

#if __has_builtin(__builtin_amdgcn_fdot2)
#define DOT2(a, b, c) __builtin_amdgcn_fdot2((a), (b), (c), false)
#else
static __device__ __forceinline__ float DOT2(half2_t a, half2_t b, float c) {
    return c + (float)a.x * (float)b.x + (float)a.y * (float)b.y;
}
#endif

#if __has_builtin(__builtin_amdgcn_rcpf)
#define RCP(x) __builtin_amdgcn_rcpf(x)
#else
#define RCP(x) (1.0f / (x))
#endif

// relaxed agent-scope (sc1, device-coherent) accesses — no fences, no RMW
static __device__ __forceinline__ unsigned long long ld_u64(const void* p) {
    return __hip_atomic_load((const unsigned long long*)p, __ATOMIC_RELAXED,
                             __HIP_MEMORY_SCOPE_AGENT);
}
static __device__ __forceinline__ void st_u64(void* p, unsigned long long v) {
    __hip_atomic_store((unsigned long long*)p, v, __ATOMIC_RELAXED,
                       __HIP_MEMORY_SCOPE_AGENT);
}

// DPP butterfly add: x + perm(x).
template <int CTRL>
static __device__ __forceinline__ float dpp_add(float x) {
    int v = __builtin_amdgcn_update_dpp(0, __builtin_bit_cast(int, x), CTRL, 0xF,
                                        0xF, true);
    return x + __builtin_bit_cast(float, v);
}
#define DPP_XOR1  0xB1   // quad_perm [1,0,3,2]
#define DPP_XOR2  0x4E   // quad_perm [2,3,0,1]
#define DPP_XOR4  0x141  // row_half_mirror
#define DPP_XOR8  0x128  // row_ror:8 (exact lane s <-> s+8 within row16)

// ---------------- f32 -> f16 convert ----------------
__global__ __launch_bounds__(256) void cvt_f32_f16(const float* __restrict__ in,
                                                   _Float16* __restrict__ out, int n) {
    int i = (blockIdx.x * 256 + threadIdx.x) * 4;
    if (i < n) {
        float4 v = *(const float4*)(in + i);
        out[i + 0] = (_Float16)v.x;
        out[i + 1] = (_Float16)v.y;
        out[i + 2] = (_Float16)v.z;
        out[i + 3] = (_Float16)v.w;
    }
}

// ---------------- init words (zero => {h=0, tag=0} == "h_0 valid") ----------------
// words[2][256][8] u64: block b's record = words[par][b][0..3] (one 64-B line).
__global__ __launch_bounds__(256) void init_state(unsigned long long* __restrict__ words) {
    int i = blockIdx.x * 256 + threadIdx.x;
    if (i < 4096) words[i] = 0ull;
}

// ---------------- x_proj GEMM: C = A @ B^T, epilogue scattered into xp2 ----------
// xp2 layout: xp2[t][b*32 + g*8 + r] where r = gate*2 + (elem&1), g = (elem>>1)&3,
// b = elem>>3. One 64-B line per block-step.
__global__ __launch_bounds__(256) void gemm_xproj(const _Float16* __restrict__ A,  // [SEQ][ISZ]
                                                  const _Float16* __restrict__ B,  // [G4H][ISZ]
                                                  _Float16* __restrict__ C) {      // [SEQ][G4H] permuted
    __shared__ _Float16 As[128 * 40];
    __shared__ _Float16 Bs[128 * 40];
    const int tid = threadIdx.x;
    const int bm = blockIdx.y, bn = blockIdx.x;
    const int wave = tid >> 6, lane = tid & 63;
    const int wr = wave >> 1, wc = wave & 1;
    const int l15 = lane & 15, lq = lane >> 4;

    float4_t acc[4][4];
#pragma unroll
    for (int im = 0; im < 4; im++)
#pragma unroll
        for (int in = 0; in < 4; in++)
#pragma unroll
            for (int r = 0; r < 4; r++) acc[im][in][r] = 0.f;

    for (int kt = 0; kt < ISZ; kt += 32) {
        __syncthreads();
#pragma unroll
        for (int ld = 0; ld < 2; ld++) {
            int c = tid + ld * 256;
            int r = c >> 2, ko = (c & 3) * 8;
            uint4 av = *(const uint4*)(A + (size_t)(bm * 128 + r) * ISZ + kt + ko);
            *(uint4*)(As + r * 40 + ko) = av;
            uint4 bv = *(const uint4*)(B + (size_t)(bn * 128 + r) * ISZ + kt + ko);
            *(uint4*)(Bs + r * 40 + ko) = bv;
        }
        __syncthreads();
        half8_t af[4], bf[4];
#pragma unroll
        for (int im = 0; im < 4; im++)
            af[im] = *(half8_t*)(As + (wr * 64 + im * 16 + l15) * 40 + lq * 8);
#pragma unroll
        for (int in = 0; in < 4; in++)
            bf[in] = *(half8_t*)(Bs + (wc * 64 + in * 16 + l15) * 40 + lq * 8);
#pragma unroll
        for (int im = 0; im < 4; im++)
#pragma unroll
            for (int in = 0; in < 4; in++)
                acc[im][in] = __builtin_amdgcn_mfma_f32_16x16x32_f16(af[im], bf[in], acc[im][in], 0, 0, 0);
    }
#pragma unroll
    for (int im = 0; im < 4; im++) {
        int mg = bm * 128 + wr * 64 + im * 16 + lq * 4;
#pragma unroll
        for (int in = 0; in < 4; in++) {
            int ng = bn * 128 + wc * 64 + in * 16 + l15;
            int gate = ng >> 11;
            int e = ng & 2047;
            int col2 = (e >> 3) * 32 + ((e >> 1) & 3) * 8 + gate * 2 + (e & 1);
#pragma unroll
            for (int r = 0; r < 4; r++)
                C[(size_t)(mg + r) * G4H + col2] = (_Float16)acc[im][in][r];
        }
    }
}

// ---------------- persistent LSTM recurrence ----------------
// Block b owns h[8b..8b+8). Wave g owns all 4 gates of elements {2g, 2g+1};
// fused word {tag32 | h_e1 | h_e0}. R9: all 4 words are combined via LDS and
// published by ONE lane as 4 back-to-back sc1 stores into the block's single
// 64-B line — one invalidation burst per step instead of 4 spread ones.
// Poll rotation: wave g lane j polls block 64g+((j+b)&63)'s 4 words.
__global__ __launch_bounds__(256, 1) void lstm_persist(
    const float* __restrict__ Whh,   // [G4H][HID] f32
    const float* __restrict__ b_ih, const float* __restrict__ b_hh,
    const _Float16* __restrict__ xp, // [SEQ][G4H] f16, permuted layout
    const float* __restrict__ fcw, const float* __restrict__ fcb,
    unsigned long long* __restrict__ words,  // [2][256][8]
    float* __restrict__ out) {
    const int b = blockIdx.x, tid = threadIdx.x;
    const int g = tid >> 6, lane = tid & 63;
    const int pblk = (g << 6) | ((lane + b) & 63);  // block this lane polls/stages

    __shared__ unsigned h_lds32[2][1280];       // parity x (64 units x 20 dwords)
    __shared__ unsigned long long pub_lds[4];   // per-wave fused words

    // --- prologue: weight slice into registers (f32 -> f16) ---
    half2_t w[8][16];
#pragma unroll
    for (int r = 0; r < 8; r++) {
        const float* wp =
            Whh + (size_t)((r >> 1) * HID + b * 8 + 2 * g + (r & 1)) * HID + lane * 32;
#pragma unroll
        for (int i = 0; i < 16; i++) {
            float2 f = *(const float2*)(wp + i * 2);
            half2_t h2;
            h2.x = (_Float16)f.x;
            h2.y = (_Float16)f.y;
            w[r][i] = h2;
        }
    }
    float bias_r = 0.f;
    if (lane < 8) {
        int row = ((lane >> 1) & 3) * HID + b * 8 + 2 * g + (lane & 1);
        bias_r = b_ih[row] + b_hh[row];
    }
    float c_reg = 0.f;  // cell state of elem 2g+(lane&1)

    const int s_dw = (pblk >> 2) * 20 + (pblk & 3) * 4;  // LDS stage dst (dwords)
    const int xpbase = b * 32 + g * 8;                   // + lane (lanes 0..7)

    for (int t = 0; t < SEQ; ++t) {
        const unsigned ut = (unsigned)t;
        const int par = t & 1;

        // x_proj prefetch: one 64-B line per block-step (permuted layout)
        float xpv = 0.f;
        if (lane < 8) xpv = (float)xp[(size_t)t * G4H + xpbase + lane];

        // poll own block's 4 self-validating words (32 B in one line)
        const unsigned long long* wp = words + (size_t)par * 2048 + pblk * 8;
        unsigned long long v0, v1, v2, v3;
        for (;;) {
            v0 = ld_u64(wp + 0);
            v1 = ld_u64(wp + 1);
            v2 = ld_u64(wp + 2);
            v3 = ld_u64(wp + 3);
            bool ok = ((unsigned)(v0 >> 32) >= ut) && ((unsigned)(v1 >> 32) >= ut) &&
                      ((unsigned)(v2 >> 32) >= ut) && ((unsigned)(v3 >> 32) >= ut);
            if (__all(ok)) break;
            __builtin_amdgcn_s_sleep(1);
        }

        // stage 8 halves of block pblk into parity LDS buffer (one b128)
        *(uint4*)&h_lds32[par][s_dw] =
            make_uint4((unsigned)v0, (unsigned)v1, (unsigned)v2, (unsigned)v3);
        __syncthreads();  // B1: h_t fully staged

        // read slice [lane*32, lane*32+32) as 4 x b128
        union {
            uint4 q[4];
            half2_t h2[16];
        } hu;
        const uint4* hp4 = (const uint4*)((const char*)&h_lds32[par][0] + 80 * lane);
#pragma unroll
        for (int i = 0; i < 4; i++) hu.q[i] = hp4[i];

        // matvec: 8 rows x 32 cols per lane
        float acc[8];
#pragma unroll
        for (int r = 0; r < 8; r++) {
            float a = 0.f;
#pragma unroll
            for (int i = 0; i < 16; i++) a = DOT2(w[r][i], hu.h2[i], a);
            acc[r] = a;
        }
        // reduce: DPP xor1/2/4, select, DPP xor8, shfl 16/32
#pragma unroll
        for (int r = 0; r < 8; r++) {
            acc[r] = dpp_add<DPP_XOR1>(acc[r]);
            acc[r] = dpp_add<DPP_XOR2>(acc[r]);
            acc[r] = dpp_add<DPP_XOR4>(acc[r]);
        }
        float u;
        {
            int s = lane & 7;
            float u01 = (s & 1) ? acc[1] : acc[0];
            float u23 = (s & 1) ? acc[3] : acc[2];
            float u45 = (s & 1) ? acc[5] : acc[4];
            float u67 = (s & 1) ? acc[7] : acc[6];
            float ua = (s & 2) ? u23 : u01;
            float ub = (s & 2) ? u67 : u45;
            u = (s & 4) ? ub : ua;
        }
        u = dpp_add<DPP_XOR8>(u);
        u += __shfl_xor(u, 16, 64);
        u += __shfl_xor(u, 32, 64);
        u += bias_r + xpv;  // valid in lanes 0..7 (sources of the gate shfls)

        // gates: rows [i_e0,i_e1,f_e0,f_e1,g_e0,g_e1,o_e0,o_e1] in lanes 0..7
        {
            int base = lane & 1;
            float gi = __shfl(u, base + 0, 64);
            float gf = __shfl(u, base + 2, 64);
            float gg = __shfl(u, base + 4, 64);
            float go = __shfl(u, base + 6, 64);
            float si = RCP(1.f + __expf(-gi));
            float sf = RCP(1.f + __expf(-gf));
            float so = RCP(1.f + __expf(-go));
            float tg = 1.f - 2.f * RCP(1.f + __expf(2.f * gg));
            c_reg = sf * c_reg + si * tg;
            float tc = 1.f - 2.f * RCP(1.f + __expf(2.f * c_reg));
            float h = so * tc;
            _Float16 hf = (_Float16)h;
            unsigned pk = *(unsigned short*)&hf;
            unsigned pk1 = __shfl(pk, 1, 64);
            if (lane == 0) {
                unsigned lo = pk | (pk1 << 16);
                pub_lds[g] =
                    (unsigned long long)lo | ((unsigned long long)(ut + 1) << 32);
            }
        }
        __syncthreads();  // B2: all 4 fused words deposited

        if (tid == 0) {
            // single-burst publish: 4 back-to-back sc1 stores into our line
            unsigned long long* dp = words + (size_t)((t + 1) & 1) * 2048 + b * 8;
            unsigned long long w0 = pub_lds[0], w1 = pub_lds[1];
            unsigned long long w2 = pub_lds[2], w3 = pub_lds[3];
            st_u64(dp + 0, w0);
            st_u64(dp + 1, w1);
            st_u64(dp + 2, w2);
            st_u64(dp + 3, w3);
        }
        // no barrier after publish: waves roll into the next poll; parity
        // double-buffered LDS + B1/B2 ordering keep cross-step reuse race-free
    }

    // --- final fc on h_SEQ (parity 0) by block 0 ---
    if (b == 0) {
        const int par = SEQ & 1;
        const unsigned long long* wp = words + (size_t)par * 2048 + pblk * 8;
        unsigned long long v0, v1, v2, v3;
        for (;;) {
            v0 = ld_u64(wp + 0);
            v1 = ld_u64(wp + 1);
            v2 = ld_u64(wp + 2);
            v3 = ld_u64(wp + 3);
            bool ok = ((unsigned)(v0 >> 32) >= (unsigned)SEQ) &&
                      ((unsigned)(v1 >> 32) >= (unsigned)SEQ) &&
                      ((unsigned)(v2 >> 32) >= (unsigned)SEQ) &&
                      ((unsigned)(v3 >> 32) >= (unsigned)SEQ);
            if (__all(ok)) break;
            __builtin_amdgcn_s_sleep(1);
        }
        *(uint4*)&h_lds32[par][s_dw] =
            make_uint4((unsigned)v0, (unsigned)v1, (unsigned)v2, (unsigned)v3);
        __syncthreads();
        if (g == 0) {
            union {
                uint4 q[4];
                half2_t h2[16];
            } hu;
            const uint4* hp4 = (const uint4*)((const char*)&h_lds32[par][0] + 80 * lane);
#pragma unroll
            for (int i = 0; i < 4; i++) hu.q[i] = hp4[i];
            float s = 0.f;
            const float* fw = fcw + lane * 32;
#pragma unroll
            for (int i = 0; i < 16; i++)
                s += (float)hu.h2[i].x * fw[2 * i] + (float)hu.h2[i].y * fw[2 * i + 1];
#pragma unroll
            for (int off = 1; off < 64; off <<= 1) s += __shfl_xor(s, off, 64);
            if (lane == 0) out[0] = s + fcb[0];
        }
    }
}

// ---------------- launch ----------------
extern "C" void kernel_launch(void* const* d_in, const int* in_sizes, int n_in,
                              void* d_out, int out_size, void* d_ws, size_t ws_size,
                              hipStream_t stream) {
    const float* input = (const float*)d_in[0];  // [SEQ][ISZ]
    const float* W_ih = (const float*)d_in[1];   // [G4H][ISZ]
    const float* W_hh = (const float*)d_in[2];   // [G4H][HID]
    const float* b_ih = (const float*)d_in[3];
    const float* b_hh = (const float*)d_in[4];
    const float* fc_w = (const float*)d_in[5];
    const float* fc_b = (const float*)d_in[6];
    float* out = (float*)d_out;

    char* ws = (char*)d_ws;
    _Float16* xp16 = (_Float16*)ws;               // 134,217,728 B
    _Float16* A16 = (_Float16*)(ws + 134217728);  // 8 MB (dead after gemm)
    _Float16* B16 = (_Float16*)(ws + 142606336);  // 8 MB (dead after gemm)
    // words overlay the dead A16 region (init_state runs AFTER gemm): 32 KB
    unsigned long long* words = (unsigned long long*)(ws + 134217728);

    cvt_f32_f16<<<(SEQ * ISZ) / 1024, 256, 0, stream>>>(input, A16, SEQ * ISZ);
    cvt_f32_f16<<<(G4H * ISZ) / 1024, 256, 0, stream>>>(W_ih, B16, G4H * ISZ);

    dim3 gg(G4H / 128, SEQ / 128);
    gemm_xproj<<<gg, 256, 0, stream>>>(A16, B16, xp16);

    init_state<<<16, 256, 0, stream>>>(words);  // after gemm: A16 region is dead

    lstm_persist<<<NB, 256, 0, stream>>>(W_hh, b_ih, b_hh, xp16, fc_w, fc_b,
                                         words, out);
}

// Round 10
// 15281.256 us; speedup vs baseline: 1.2516x; 1.0444x over previous
//
#include <hip/hip_runtime.h>
#include <hip/hip_bf16.h>

// ---------------- types ----------------
typedef _Float16 half2_t __attribute__((ext_vector_type(2)));
typedef _Float16 half8_t __attribute__((ext_vector_type(8)));
typedef float float4_t __attribute__((ext_vector_type(4)));

#define SEQ   8192
#define ISZ   512
#define HID   2048
#define G4H   8192   // 4*HID
#define NB    256    // persistent blocks (== CU count)

#if __has_builtin(__builtin_amdgcn_fdot2)
#define DOT2(a, b, c) __builtin_amdgcn_fdot2((a), (b), (c), false)
#else
static __device__ __forceinline__ float DOT2(half2_t a, half2_t b, float c) {
    return c + (float)a.x * (float)b.x + (float)a.y * (float)b.y;
}
#endif

#if __has_builtin(__builtin_amdgcn_rcpf)
#define RCP(x) __builtin_amdgcn_rcpf(x)
#else
#define RCP(x) (1.0f / (x))
#endif

// relaxed agent-scope (sc1, device-coherent) accesses — no fences, no RMW
static __device__ __forceinline__ unsigned long long ld_u64(const void* p) {
    return __hip_atomic_load((const unsigned long long*)p, __ATOMIC_RELAXED,
                             __HIP_MEMORY_SCOPE_AGENT);
}
static __device__ __forceinline__ void st_u64(void* p, unsigned long long v) {
    __hip_atomic_store((unsigned long long*)p, v, __ATOMIC_RELAXED,
                       __HIP_MEMORY_SCOPE_AGENT);
}

// DPP butterfly add: x + perm(x).
template <int CTRL>
static __device__ __forceinline__ float dpp_add(float x) {
    int v = __builtin_amdgcn_update_dpp(0, __builtin_bit_cast(int, x), CTRL, 0xF,
                                        0xF, true);
    return x + __builtin_bit_cast(float, v);
}
#define DPP_XOR1  0xB1   // quad_perm [1,0,3,2]
#define DPP_XOR2  0x4E   // quad_perm [2,3,0,1]
#define DPP_XOR4  0x141  // row_half_mirror
#define DPP_XOR8  0x128  // row_ror:8 (exact lane s <-> s+8 within row16)

// ---------------- f32 -> f16 convert ----------------
__global__ __launch_bounds__(256) void cvt_f32_f16(const float* __restrict__ in,
                                                   _Float16* __restrict__ out, int n) {
    int i = (blockIdx.x * 256 + threadIdx.x) * 4;
    if (i < n) {
        float4 v = *(const float4*)(in + i);
        out[i + 0] = (_Float16)v.x;
        out[i + 1] = (_Float16)v.y;
        out[i + 2] = (_Float16)v.z;
        out[i + 3] = (_Float16)v.w;
    }
}

// ---------------- init words (zero => {h=0, tag=0} == "h_0 valid") ----------------
// words[2][256][8] u64: block b's record = words[par][b][0..3] (one 64-B line).
__global__ __launch_bounds__(256) void init_state(unsigned long long* __restrict__ words) {
    int i = blockIdx.x * 256 + threadIdx.x;
    if (i < 4096) words[i] = 0ull;
}

// ---------------- x_proj GEMM: C = A @ B^T, epilogue scattered into xp2 ----------
// xp2 layout: xp2[t][b*32 + g*8 + r] where r = gate*2 + (elem&1), g = (elem>>1)&3,
// b = elem>>3. One 64-B line per block-step.
__global__ __launch_bounds__(256) void gemm_xproj(const _Float16* __restrict__ A,  // [SEQ][ISZ]
                                                  const _Float16* __restrict__ B,  // [G4H][ISZ]
                                                  _Float16* __restrict__ C) {      // [SEQ][G4H] permuted
    __shared__ _Float16 As[128 * 40];
    __shared__ _Float16 Bs[128 * 40];
    const int tid = threadIdx.x;
    const int bm = blockIdx.y, bn = blockIdx.x;
    const int wave = tid >> 6, lane = tid & 63;
    const int wr = wave >> 1, wc = wave & 1;
    const int l15 = lane & 15, lq = lane >> 4;

    float4_t acc[4][4];
#pragma unroll
    for (int im = 0; im < 4; im++)
#pragma unroll
        for (int in = 0; in < 4; in++)
#pragma unroll
            for (int r = 0; r < 4; r++) acc[im][in][r] = 0.f;

    for (int kt = 0; kt < ISZ; kt += 32) {
        __syncthreads();
#pragma unroll
        for (int ld = 0; ld < 2; ld++) {
            int c = tid + ld * 256;
            int r = c >> 2, ko = (c & 3) * 8;
            uint4 av = *(const uint4*)(A + (size_t)(bm * 128 + r) * ISZ + kt + ko);
            *(uint4*)(As + r * 40 + ko) = av;
            uint4 bv = *(const uint4*)(B + (size_t)(bn * 128 + r) * ISZ + kt + ko);
            *(uint4*)(Bs + r * 40 + ko) = bv;
        }
        __syncthreads();
        half8_t af[4], bf[4];
#pragma unroll
        for (int im = 0; im < 4; im++)
            af[im] = *(half8_t*)(As + (wr * 64 + im * 16 + l15) * 40 + lq * 8);
#pragma unroll
        for (int in = 0; in < 4; in++)
            bf[in] = *(half8_t*)(Bs + (wc * 64 + in * 16 + l15) * 40 + lq * 8);
#pragma unroll
        for (int im = 0; im < 4; im++)
#pragma unroll
            for (int in = 0; in < 4; in++)
                acc[im][in] = __builtin_amdgcn_mfma_f32_16x16x32_f16(af[im], bf[in], acc[im][in], 0, 0, 0);
    }
#pragma unroll
    for (int im = 0; im < 4; im++) {
        int mg = bm * 128 + wr * 64 + im * 16 + lq * 4;
#pragma unroll
        for (int in = 0; in < 4; in++) {
            int ng = bn * 128 + wc * 64 + in * 16 + l15;
            int gate = ng >> 11;
            int e = ng & 2047;
            int col2 = (e >> 3) * 32 + ((e >> 1) & 3) * 8 + gate * 2 + (e & 1);
#pragma unroll
            for (int r = 0; r < 4; r++)
                C[(size_t)(mg + r) * G4H + col2] = (_Float16)acc[im][in][r];
        }
    }
}

// ---------------- persistent LSTM recurrence ----------------
// R7 structure + R10 changes:
//  * predicated polls: lanes re-load ONLY still-missing word pairs (kills the
//    64x retry amplification of the __all() loop)
//  * xp[t+1] prefetched during step t (HBM miss off the critical path)
// Block b owns h[8b..8b+8). Wave g owns all 4 gates of elements {2g, 2g+1};
// fused self-validating word {tag32 | h_e1 | h_e0}; per-wave immediate publish.
// Poll rotation: wave g lane j polls block 64g+((j+b)&63)'s 4 words (1 line).
__global__ __launch_bounds__(256, 1) void lstm_persist(
    const float* __restrict__ Whh,   // [G4H][HID] f32
    const float* __restrict__ b_ih, const float* __restrict__ b_hh,
    const _Float16* __restrict__ xp, // [SEQ][G4H] f16, permuted layout
    const float* __restrict__ fcw, const float* __restrict__ fcb,
    unsigned long long* __restrict__ words,  // [2][256][8]
    float* __restrict__ out) {
    const int b = blockIdx.x, tid = threadIdx.x;
    const int g = tid >> 6, lane = tid & 63;
    const int pblk = (g << 6) | ((lane + b) & 63);  // block this lane polls/stages

    __shared__ unsigned h_lds32[2][1280];  // parity x (64 units x 20 dwords)

    // --- prologue: weight slice into registers (f32 -> f16) ---
    half2_t w[8][16];
#pragma unroll
    for (int r = 0; r < 8; r++) {
        const float* wp =
            Whh + (size_t)((r >> 1) * HID + b * 8 + 2 * g + (r & 1)) * HID + lane * 32;
#pragma unroll
        for (int i = 0; i < 16; i++) {
            float2 f = *(const float2*)(wp + i * 2);
            half2_t h2;
            h2.x = (_Float16)f.x;
            h2.y = (_Float16)f.y;
            w[r][i] = h2;
        }
    }
    float bias_r = 0.f;
    if (lane < 8) {
        int row = ((lane >> 1) & 3) * HID + b * 8 + 2 * g + (lane & 1);
        bias_r = b_ih[row] + b_hh[row];
    }
    float c_reg = 0.f;  // cell state of elem 2g+(lane&1)

    const int s_dw = (pblk >> 2) * 20 + (pblk & 3) * 4;  // LDS stage dst (dwords)
    const int xpbase = b * 32 + g * 8;                   // + lane (lanes 0..7)

    // xp prefetch pipeline: xpv_cur holds xp[t] by loop entry
    float xpv_cur = 0.f;
    if (lane < 8) xpv_cur = (float)xp[xpbase + lane];

    for (int t = 0; t < SEQ; ++t) {
        const unsigned ut = (unsigned)t;
        const int par = t & 1;

        // prefetch xp[t+1]; independent of everything -> overlaps whole step
        float xpv_next = 0.f;
        if (lane < 8 && t + 1 < SEQ)
            xpv_next = (float)xp[(size_t)(t + 1) * G4H + xpbase + lane];
        const float xpv = xpv_cur;

        // poll own block's 4 self-validating words; re-load ONLY missing pairs
        const unsigned long long* wp = words + (size_t)par * 2048 + pblk * 8;
        unsigned long long v0, v1, v2, v3;
        {
            bool g01 = false, g23 = false;
            for (;;) {
                if (!g01) {
                    v0 = ld_u64(wp + 0);
                    v1 = ld_u64(wp + 1);
                    g01 = ((unsigned)(v0 >> 32) >= ut) && ((unsigned)(v1 >> 32) >= ut);
                }
                if (!g23) {
                    v2 = ld_u64(wp + 2);
                    v3 = ld_u64(wp + 3);
                    g23 = ((unsigned)(v2 >> 32) >= ut) && ((unsigned)(v3 >> 32) >= ut);
                }
                if (__all(g01 && g23)) break;
                __builtin_amdgcn_s_sleep(1);
            }
        }

        // stage 8 halves of block pblk into parity LDS buffer (one b128)
        *(uint4*)&h_lds32[par][s_dw] =
            make_uint4((unsigned)v0, (unsigned)v1, (unsigned)v2, (unsigned)v3);
        __syncthreads();  // the ONLY barrier: h_t fully staged

        // read slice [lane*32, lane*32+32) as 4 x b128
        union {
            uint4 q[4];
            half2_t h2[16];
        } hu;
        const uint4* hp4 = (const uint4*)((const char*)&h_lds32[par][0] + 80 * lane);
#pragma unroll
        for (int i = 0; i < 4; i++) hu.q[i] = hp4[i];

        // matvec: 8 rows x 32 cols per lane
        float acc[8];
#pragma unroll
        for (int r = 0; r < 8; r++) {
            float a = 0.f;
#pragma unroll
            for (int i = 0; i < 16; i++) a = DOT2(w[r][i], hu.h2[i], a);
            acc[r] = a;
        }
        // reduce: DPP xor1/2/4, select, DPP xor8, shfl 16/32
#pragma unroll
        for (int r = 0; r < 8; r++) {
            acc[r] = dpp_add<DPP_XOR1>(acc[r]);
            acc[r] = dpp_add<DPP_XOR2>(acc[r]);
            acc[r] = dpp_add<DPP_XOR4>(acc[r]);
        }
        float u;
        {
            int s = lane & 7;
            float u01 = (s & 1) ? acc[1] : acc[0];
            float u23 = (s & 1) ? acc[3] : acc[2];
            float u45 = (s & 1) ? acc[5] : acc[4];
            float u67 = (s & 1) ? acc[7] : acc[6];
            float ua = (s & 2) ? u23 : u01;
            float ub = (s & 2) ? u67 : u45;
            u = (s & 4) ? ub : ua;
        }
        u = dpp_add<DPP_XOR8>(u);
        u += __shfl_xor(u, 16, 64);
        u += __shfl_xor(u, 32, 64);
        u += bias_r + xpv;  // valid in lanes 0..7 (sources of the gate shfls)

        // gates: rows [i_e0,i_e1,f_e0,f_e1,g_e0,g_e1,o_e0,o_e1] in lanes 0..7
        {
            int base = lane & 1;
            float gi = __shfl(u, base + 0, 64);
            float gf = __shfl(u, base + 2, 64);
            float gg = __shfl(u, base + 4, 64);
            float go = __shfl(u, base + 6, 64);
            float si = RCP(1.f + __expf(-gi));
            float sf = RCP(1.f + __expf(-gf));
            float so = RCP(1.f + __expf(-go));
            float tg = 1.f - 2.f * RCP(1.f + __expf(2.f * gg));
            c_reg = sf * c_reg + si * tg;
            float tc = 1.f - 2.f * RCP(1.f + __expf(2.f * c_reg));
            float h = so * tc;
            _Float16 hf = (_Float16)h;
            unsigned pk = *(unsigned short*)&hf;
            unsigned pk1 = __shfl(pk, 1, 64);
            if (lane == 0) {
                unsigned lo = pk | (pk1 << 16);
                unsigned long long wword =
                    (unsigned long long)lo | ((unsigned long long)(ut + 1) << 32);
                st_u64(words + (size_t)((t + 1) & 1) * 2048 + b * 8 + g, wword);
            }
        }
        xpv_cur = xpv_next;
        // parity-double-buffered LDS + B1 ordering make cross-step reuse race-free
    }

    // --- final fc on h_SEQ (parity 0) by block 0 ---
    if (b == 0) {
        const int par = SEQ & 1;
        const unsigned long long* wp = words + (size_t)par * 2048 + pblk * 8;
        unsigned long long v0, v1, v2, v3;
        {
            bool g01 = false, g23 = false;
            for (;;) {
                if (!g01) {
                    v0 = ld_u64(wp + 0);
                    v1 = ld_u64(wp + 1);
                    g01 = ((unsigned)(v0 >> 32) >= (unsigned)SEQ) &&
                          ((unsigned)(v1 >> 32) >= (unsigned)SEQ);
                }
                if (!g23) {
                    v2 = ld_u64(wp + 2);
                    v3 = ld_u64(wp + 3);
                    g23 = ((unsigned)(v2 >> 32) >= (unsigned)SEQ) &&
                          ((unsigned)(v3 >> 32) >= (unsigned)SEQ);
                }
                if (__all(g01 && g23)) break;
                __builtin_amdgcn_s_sleep(1);
            }
        }
        *(uint4*)&h_lds32[par][s_dw] =
            make_uint4((unsigned)v0, (unsigned)v1, (unsigned)v2, (unsigned)v3);
        __syncthreads();
        if (g == 0) {
            union {
                uint4 q[4];
                half2_t h2[16];
            } hu;
            const uint4* hp4 = (const uint4*)((const char*)&h_lds32[par][0] + 80 * lane);
#pragma unroll
            for (int i = 0; i < 4; i++) hu.q[i] = hp4[i];
            float s = 0.f;
            const float* fw = fcw + lane * 32;
#pragma unroll
            for (int i = 0; i < 16; i++)
                s += (float)hu.h2[i].x * fw[2 * i] + (float)hu.h2[i].y * fw[2 * i + 1];
#pragma unroll
            for (int off = 1; off < 64; off <<= 1) s += __shfl_xor(s, off, 64);
            if (lane == 0) out[0] = s + fcb[0];
        }
    }
}

// ---------------- launch ----------------
extern "C" void kernel_launch(void* const* d_in, const int* in_sizes, int n_in,
                              void* d_out, int out_size, void* d_ws, size_t ws_size,
                              hipStream_t stream) {
    const float* input = (const float*)d_in[0];  // [SEQ][ISZ]
    const float* W_ih = (const float*)d_in[1];   // [G4H][ISZ]
    const float* W_hh = (const float*)d_in[2];   // [G4H][HID]
    const float* b_ih = (const float*)d_in[3];
    const float* b_hh = (const float*)d_in[4];
    const float* fc_w = (const float*)d_in[5];
    const float* fc_b = (const float*)d_in[6];
    float* out = (float*)d_out;

    char* ws = (char*)d_ws;
    _Float16* xp16 = (_Float16*)ws;               // 134,217,728 B
    _Float16* A16 = (_Float16*)(ws + 134217728);  // 8 MB (dead after gemm)
    _Float16* B16 = (_Float16*)(ws + 142606336);  // 8 MB (dead after gemm)
    // words overlay the dead A16 region (init_state runs AFTER gemm): 32 KB
    unsigned long long* words = (unsigned long long*)(ws + 134217728);

    cvt_f32_f16<<<(SEQ * ISZ) / 1024, 256, 0, stream>>>(input, A16, SEQ * ISZ);
    cvt_f32_f16<<<(G4H * ISZ) / 1024, 256, 0, stream>>>(W_ih, B16, G4H * ISZ);

    dim3 gg(G4H / 128, SEQ / 128);
    gemm_xproj<<<gg, 256, 0, stream>>>(A16, B16, xp16);

    init_state<<<16, 256, 0, stream>>>(words);  // after gemm: A16 region is dead

    lstm_persist<<<NB, 256, 0, stream>>>(W_hh, b_ih, b_hh, xp16, fc_w, fc_b,
                                         words, out);
}